// Round 9
// baseline (265.485 us; speedup 1.0000x reference)
//
#include <hip/hip_runtime.h>

#define DIN 128
#define DG 64

typedef __attribute__((ext_vector_type(8))) short short8;
typedef __attribute__((ext_vector_type(4))) float f32x4;

// ---- bf16 helpers (RNE) ----
static __device__ __forceinline__ unsigned short f2bf(float x) {
    unsigned u = __builtin_bit_cast(unsigned, x);
    u = (u + 0x7FFF + ((u >> 16) & 1)) >> 16;
    return (unsigned short)u;
}
static __device__ __forceinline__ float bf2f(unsigned short s) {
    return __builtin_bit_cast(float, (unsigned)s << 16);
}

// ---------- K1: degree+slot capture, fused with W0|W1 -> Bt transpose ----------
__global__ void k_deg_wt(const int* __restrict__ rows, int* __restrict__ deg,
                         int* __restrict__ slot, int E, int nDeg,
                         const float* __restrict__ W0, const float* __restrict__ W1,
                         unsigned short* __restrict__ Bt) {
    int b = blockIdx.x;
    if (b < nDeg) {
        int e = b * 256 + threadIdx.x;
        if (e < E) slot[e] = atomicAdd(&deg[rows[e]], 1);
    } else {
        int k = b - nDeg;  // 0..127
        int c = threadIdx.x;
        const float* W = (c < 128) ? W0 : W1;
        Bt[c * 128 + k] = f2bf(W[k * 128 + (c & 127)]);
    }
}

// ---------- K2: per-block exclusive scan (1024 elems/block) ----------
__global__ __launch_bounds__(1024) void k_scan1(const int* __restrict__ deg,
                                                int* __restrict__ rowptr,
                                                int* __restrict__ bsum, int n) {
    __shared__ int wsum[16];
    __shared__ int woff[16];
    int tid = threadIdx.x;
    int lane = tid & 63, w = tid >> 6;
    int i = blockIdx.x * 1024 + tid;
    int v = (i < n) ? deg[i] : 0;
    int x = v;
    #pragma unroll
    for (int off = 1; off < 64; off <<= 1) {
        int y = __shfl_up(x, off, 64);
        if (lane >= off) x += y;
    }
    if (lane == 63) wsum[w] = x;
    __syncthreads();
    if (w == 0) {
        int t = (lane < 16) ? wsum[lane] : 0;
        int xx = t;
        #pragma unroll
        for (int off = 1; off < 16; off <<= 1) {
            int y = __shfl_up(xx, off, 64);
            if (lane >= off) xx += y;
        }
        if (lane < 16) woff[lane] = xx - t;  // exclusive
    }
    __syncthreads();
    if (i < n) rowptr[i] = x - v + woff[w];
    if (tid == 1023) bsum[blockIdx.x] = woff[15] + wsum[15];
}

// ---------- K4: fused big kernel ----------
// y==0 : zj = feat @ Wp (f32, gate-critical) + gpart/fdotg dots
// y==1 : h0 (f32) + h1 (bf16) via 16x16x32 bf16 MFMA + a_self/a_neigh
// y==2 : scan finalize (add bsum prefix to rowptr; write rowptr[n])
#define AS_LD 132
#define ALD 136
#define SMEM_BYTES 25088  // max(32*132*4 + 32*64*4, 64*136*2 + 1024)

static __device__ __forceinline__ void zj_body(
    const float* __restrict__ feat, const float* __restrict__ Wp,
    const float* __restrict__ Wg,
    float* __restrict__ zj, float* __restrict__ gpart, float* __restrict__ fdotg,
    int N, char* smem) {
    float* As = (float*)smem;
    float* Bs = (float*)(smem + 32 * AS_LD * 4);
    int tid = threadIdx.x;
    int tx = tid & 15, ty = tid >> 4;
    int m0 = blockIdx.x * 128;
    if (m0 >= N) return;
    float acc[8][4];
    #pragma unroll
    for (int r = 0; r < 8; ++r)
        #pragma unroll
        for (int c = 0; c < 4; ++c) acc[r][c] = 0.f;
    float gdot[8], fdot[8];
    #pragma unroll
    for (int r = 0; r < 8; ++r) { gdot[r] = 0.f; fdot[r] = 0.f; }
    for (int kc = 0; kc < 128; kc += 32) {
        for (int i = tid; i < 1024; i += 256) {
            int m = i >> 3, kq = (i & 7) << 2;
            int node = m0 + m;
            float4 f;
            if (node < N) f = *(const float4*)&feat[(size_t)node * 128 + kc + kq];
            else          f = make_float4(0.f, 0.f, 0.f, 0.f);
            As[(kq + 0) * AS_LD + m] = f.x;
            As[(kq + 1) * AS_LD + m] = f.y;
            As[(kq + 2) * AS_LD + m] = f.z;
            As[(kq + 3) * AS_LD + m] = f.w;
        }
        for (int i = tid; i < 512; i += 256) {
            int k = i >> 4, cq = (i & 15) << 2;
            *(float4*)&Bs[k * 64 + cq] = *(const float4*)&Wp[(size_t)(kc + k) * 64 + cq];
        }
        __syncthreads();
        #pragma unroll 8
        for (int kk = 0; kk < 32; ++kk) {
            const float* ar = &As[kk * AS_LD];
            float4 a0 = *(const float4*)(ar + 4 * tx);
            float4 a1 = *(const float4*)(ar + 64 + 4 * tx);
            float4 b0v = *(const float4*)&Bs[kk * 64 + 4 * ty];
            float a[8] = {a0.x, a0.y, a0.z, a0.w, a1.x, a1.y, a1.z, a1.w};
            #pragma unroll
            for (int r = 0; r < 8; ++r) {
                acc[r][0] += a[r] * b0v.x; acc[r][1] += a[r] * b0v.y;
                acc[r][2] += a[r] * b0v.z; acc[r][3] += a[r] * b0v.w;
            }
            float g1 = Wg[kc + kk];        // Wg[0:128]   -> gpart
            float g2 = Wg[192 + kc + kk];  // Wg[192:320] -> fdotg
            #pragma unroll
            for (int r = 0; r < 8; ++r) { gdot[r] += a[r] * g1; fdot[r] += a[r] * g2; }
        }
        __syncthreads();
    }
    #pragma unroll
    for (int r = 0; r < 8; ++r) {
        int node = m0 + ((r < 4) ? (4 * tx + r) : (64 + 4 * tx + (r - 4)));
        if (node >= N) continue;
        *(float4*)&zj[(size_t)node * 64 + 4 * ty] =
            make_float4(acc[r][0], acc[r][1], acc[r][2], acc[r][3]);
        if (ty == 0) { gpart[node] = gdot[r]; fdotg[node] = fdot[r]; }
    }
}

static __device__ __forceinline__ void mfma_body(
    const float* __restrict__ feat, const unsigned short* __restrict__ Bt,
    const float* __restrict__ b0, const float* __restrict__ b1,
    const float* __restrict__ att,
    float* __restrict__ h0, unsigned short* __restrict__ hb,
    float* __restrict__ a_self, float* __restrict__ a_neigh, int N, char* smem) {
    unsigned short* As = (unsigned short*)smem;
    float* sredA = (float*)(smem + 64 * ALD * 2);
    float* nredA = sredA + 128;
    int tid = threadIdx.x;
    int m0 = blockIdx.x * 64;
    // stage A: 64 rows x 128 k, f32 -> bf16 inline (32 float4-chunks/row)
    for (int i = tid; i < 2048; i += 256) {
        int row = i >> 5, ch = i & 31;
        int node = m0 + row;
        float4 f;
        if (node < N) f = *(const float4*)&feat[(size_t)node * 128 + ch * 4];
        else          f = make_float4(0.f, 0.f, 0.f, 0.f);
        unsigned p0 = (unsigned)f2bf(f.x) | ((unsigned)f2bf(f.y) << 16);
        unsigned p1 = (unsigned)f2bf(f.z) | ((unsigned)f2bf(f.w) << 16);
        *(uint2*)&As[row * ALD + ch * 4] = make_uint2(p0, p1);
    }
    __syncthreads();
    int w = tid >> 6, lane = tid & 63;
    int lm = lane & 15, q = lane >> 4;
    f32x4 acc[4][4];  // [row-tile][col-tile]
    #pragma unroll
    for (int rt = 0; rt < 4; ++rt)
        #pragma unroll
        for (int ct = 0; ct < 4; ++ct)
            #pragma unroll
            for (int r = 0; r < 4; ++r) acc[rt][ct][r] = 0.f;
    #pragma unroll
    for (int ks = 0; ks < 4; ++ks) {
        short8 a[4], b[4];
        #pragma unroll
        for (int rt = 0; rt < 4; ++rt)
            a[rt] = *(const short8*)&As[(rt * 16 + lm) * ALD + ks * 32 + q * 8];
        #pragma unroll
        for (int ct = 0; ct < 4; ++ct)
            b[ct] = *(const short8*)&Bt[(size_t)(w * 64 + ct * 16 + lm) * 128 + ks * 32 + q * 8];
        #pragma unroll
        for (int rt = 0; rt < 4; ++rt)
            #pragma unroll
            for (int ct = 0; ct < 4; ++ct)
                acc[rt][ct] = __builtin_amdgcn_mfma_f32_16x16x32_bf16(a[rt], b[ct], acc[rt][ct], 0, 0, 0);
    }
    // epilogue: bias + relu, store, att-dot partials
    float sacc[4][4];
    #pragma unroll
    for (int rt = 0; rt < 4; ++rt)
        #pragma unroll
        for (int r = 0; r < 4; ++r) sacc[rt][r] = 0.f;
    #pragma unroll
    for (int ct = 0; ct < 4; ++ct) {
        int col = w * 64 + ct * 16 + lm;  // 0..255, wave-uniform half
        float attc = att[col];
        float bias = (w < 2) ? b0[col] : b1[col - 128];
        #pragma unroll
        for (int rt = 0; rt < 4; ++rt) {
            #pragma unroll
            for (int r = 0; r < 4; ++r) {
                float v = acc[rt][ct][r] + bias;
                v = fmaxf(v, 0.f);
                sacc[rt][r] += v * attc;
                int node = m0 + rt * 16 + q * 4 + r;
                if (node < N) {
                    if (w < 2) h0[(size_t)node * 128 + col] = v;
                    else       hb[(size_t)node * 128 + (col - 128)] = f2bf(v);
                }
            }
        }
    }
    float* red = (w < 2) ? sredA : nredA;
    #pragma unroll
    for (int rt = 0; rt < 4; ++rt)
        #pragma unroll
        for (int r = 0; r < 4; ++r) {
            float s = sacc[rt][r];
            s += __shfl_xor(s, 1, 64); s += __shfl_xor(s, 2, 64);
            s += __shfl_xor(s, 4, 64); s += __shfl_xor(s, 8, 64);
            if (lm == 0) red[(w & 1) * 64 + rt * 16 + q * 4 + r] = s;
        }
    __syncthreads();
    if (tid < 64) {
        int node = m0 + tid;
        if (node < N) {
            float s  = sredA[tid] + sredA[64 + tid];
            float nn = nredA[tid] + nredA[64 + tid];
            a_self[node]  = (s  >= 0.f) ? s  : 0.2f * s;
            a_neigh[node] = (nn >= 0.f) ? nn : 0.2f * nn;
        }
    }
}

static __device__ __forceinline__ void scanfin_body(
    int* __restrict__ rowptr, const int* __restrict__ bsum, int nbs, int n) {
    int b = blockIdx.x;
    int i = b * 256 + threadIdx.x;
    if (b * 256 > n) return;
    int seg = (b * 256) >> 10;  // block lies entirely in one 1024-segment
    int pref = 0;
    for (int t = 0; t < seg; ++t) pref += bsum[t];
    if (i < n) rowptr[i] += pref;
    else if (i == n) {
        int tot = pref;
        for (int t = seg; t < nbs; ++t) tot += bsum[t];
        rowptr[n] = tot;
    }
}

__global__ __launch_bounds__(256) void k_fused(
    const float* __restrict__ feat, const float* __restrict__ Wp,
    const unsigned short* __restrict__ Bt,
    const float* __restrict__ b0, const float* __restrict__ b1,
    const float* __restrict__ att, const float* __restrict__ Wg,
    float* __restrict__ h0, unsigned short* __restrict__ hb,
    float* __restrict__ zj, float* __restrict__ gpart, float* __restrict__ fdotg,
    float* __restrict__ a_self, float* __restrict__ a_neigh,
    int* __restrict__ rowptr, const int* __restrict__ bsum, int nbs, int nsc, int N) {
    __shared__ __align__(16) char smem[SMEM_BYTES];
    if (blockIdx.y == 0)
        zj_body(feat, Wp, Wg, zj, gpart, fdotg, N, smem);
    else if (blockIdx.y == 1)
        mfma_body(feat, Bt, b0, b1, att, h0, hb, a_self, a_neigh, N, smem);
    else if (blockIdx.x < nsc)
        scanfin_body(rowptr, bsum, nbs, N);
}

// ---------- K5: scatter final edge meta into CSR slot ----------
__global__ void k_scatter_meta(const int* __restrict__ rows, const int* __restrict__ cols,
                               const float* __restrict__ vals,
                               const int* __restrict__ rowptr, const int* __restrict__ slot,
                               const float* __restrict__ a_neigh, const float* __restrict__ fdotg,
                               float4* __restrict__ meta, int E) {
    int e = blockIdx.x * blockDim.x + threadIdx.x;
    if (e < E) {
        int c = cols[e];
        int dst = rowptr[rows[e]] + slot[e];
        meta[dst] = make_float4(__builtin_bit_cast(float, c),
                                a_neigh[c], vals[e] * fdotg[c], 0.f);
    }
}

// ---------- K6: per-row CSR aggregation, deep-batched gathers ----------
template<int C>
static __device__ __forceinline__ void agg_chunk_m(
    const float4* __restrict__ meta, int j, int je, int E, int lane, float asr,
    const unsigned short* __restrict__ hb, const float* __restrict__ zj,
    float2& acca, float& zmax, float& vfsum) {
    float4 m[C]; bool act[C];
    #pragma unroll
    for (int t = 0; t < C; ++t) {
        int jj = j + t;
        act[t] = jj < je;
        m[t] = meta[min(jj, E - 1)];
    }
    ushort2 hv[C]; float zv[C];
    #pragma unroll
    for (int t = 0; t < C; ++t) {
        int c = __builtin_bit_cast(int, m[t].x);
        hv[t] = ((const ushort2*)(hb + (size_t)c * 128))[lane];
        zv[t] = zj[(size_t)c * 64 + lane];
    }
    #pragma unroll
    for (int t = 0; t < C; ++t) {
        float es = act[t] ? (asr + m[t].y) : 0.f;
        acca.x += es * bf2f(hv[t].x);
        acca.y += es * bf2f(hv[t].y);
        zmax = fmaxf(zmax, act[t] ? zv[t] : -__builtin_inff());
        vfsum += act[t] ? m[t].z : 0.f;
    }
}

__global__ __launch_bounds__(256) void k_aggregate(
    const float4* __restrict__ meta, const int* __restrict__ rowptr,
    const float* __restrict__ h0, const unsigned short* __restrict__ hb,
    const float* __restrict__ zj,
    const float* __restrict__ a_self, const float* __restrict__ gpart,
    const float* __restrict__ Wg,
    const float* __restrict__ scale0, const float* __restrict__ offset0,
    const float* __restrict__ scale1, const float* __restrict__ offset1,
    float* __restrict__ out, int N, int E) {
    int r = blockIdx.x * 4 + (threadIdx.x >> 6);
    int lane = threadIdx.x & 63;
    if (r >= N) return;
    int jb = rowptr[r], je = rowptr[r + 1];
    // hoisted loads: independent of the gather chain, overlap its latency
    float asr = a_self[r];
    float gp  = gpart[r];
    float wgl = Wg[128 + lane];
    float2 x0 = ((const float2*)(h0 + (size_t)r * 128))[lane];
    float2 sc0 = ((const float2*)scale0)[lane], of0 = ((const float2*)offset0)[lane];
    float2 sc1 = ((const float2*)scale1)[lane], of1 = ((const float2*)offset1)[lane];
    float2 acca = {0.f, 0.f};
    float zmax = -__builtin_inff();
    float vfsum = 0.f;
    // first 16 edges in one deep batch (covers ~92% of rows fully), then 8-chunks
    agg_chunk_m<16>(meta, jb, je, E, lane, asr, hb, zj, acca, zmax, vfsum);
    for (int j = jb + 16; j < je; j += 8)
        agg_chunk_m<8>(meta, j, je, E, lane, asr, hb, zj, acca, zmax, vfsum);
    if (jb == je) zmax = 0.f;  // empty segment: -inf -> 0
    float gs = zmax * wgl;
    #pragma unroll
    for (int off = 32; off; off >>= 1) gs += __shfl_xor(gs, off, 64);
    float gate = gp + gs + vfsum;  // all-f32 gate path (sign matters)
    float2 ag = {acca.x * gate, acca.y * gate};
    // BN on h0 row
    float m0s = x0.x + x0.y;
    #pragma unroll
    for (int off = 32; off; off >>= 1) m0s += __shfl_xor(m0s, off, 64);
    float m0 = m0s * (1.f / 128.f);
    float d0x = x0.x - m0, d0y = x0.y - m0;
    float v0s = d0x * d0x + d0y * d0y;
    #pragma unroll
    for (int off = 32; off; off >>= 1) v0s += __shfl_xor(v0s, off, 64);
    float inv0 = rsqrtf(v0s * (1.f / 128.f) + 1e-9f);
    // BN on gated aggregation
    float m1s = ag.x + ag.y;
    #pragma unroll
    for (int off = 32; off; off >>= 1) m1s += __shfl_xor(m1s, off, 64);
    float m1 = m1s * (1.f / 128.f);
    float d1x = ag.x - m1, d1y = ag.y - m1;
    float v1s = d1x * d1x + d1y * d1y;
    #pragma unroll
    for (int off = 32; off; off >>= 1) v1s += __shfl_xor(v1s, off, 64);
    float inv1 = rsqrtf(v1s * (1.f / 128.f) + 1e-9f);
    float2 o;
    o.x = d0x * sc0.x * inv0 + of0.x + d1x * sc1.x * inv1 + of1.x;
    o.y = d0y * sc0.y * inv0 + of0.y + d1y * sc1.y * inv1 + of1.y;
    ((float2*)(out + (size_t)r * 128))[lane] = o;
}

extern "C" void kernel_launch(void* const* d_in, const int* in_sizes, int n_in,
                              void* d_out, int out_size, void* d_ws, size_t ws_size,
                              hipStream_t stream) {
    const int*   rows   = (const int*)d_in[0];
    const int*   cols   = (const int*)d_in[1];
    const float* vals   = (const float*)d_in[2];
    const float* feat   = (const float*)d_in[3];
    const float* W0     = (const float*)d_in[4];
    const float* b0     = (const float*)d_in[5];
    const float* W1     = (const float*)d_in[6];
    const float* b1     = (const float*)d_in[7];
    const float* att    = (const float*)d_in[8];
    const float* Wp     = (const float*)d_in[9];
    const float* Wg     = (const float*)d_in[10];
    const float* offset0 = (const float*)d_in[11];
    const float* scale0  = (const float*)d_in[12];
    const float* offset1 = (const float*)d_in[13];
    const float* scale1  = (const float*)d_in[14];
    float* out = (float*)d_out;

    const int E = in_sizes[0];
    const int N = in_sizes[3] / DIN;
    const int Npad = (N + 63) & ~63;

    char* ws = (char*)d_ws;
    float* h0          = (float*)ws;          ws += (size_t)N * 128 * sizeof(float);
    unsigned short* hb = (unsigned short*)ws; ws += (size_t)N * 128 * sizeof(unsigned short);
    float* zj          = (float*)ws;          ws += (size_t)N * 64 * sizeof(float);
    unsigned short* Bt = (unsigned short*)ws; ws += (size_t)256 * 128 * sizeof(unsigned short);
    float* a_self  = (float*)ws; ws += (size_t)N * sizeof(float);
    float* a_neigh = (float*)ws; ws += (size_t)N * sizeof(float);
    float* gpart   = (float*)ws; ws += (size_t)N * sizeof(float);
    float* fdotg   = (float*)ws; ws += (size_t)N * sizeof(float);
    int* deg      = (int*)ws; ws += (size_t)(N + 1) * sizeof(int);
    int* rowptr   = (int*)ws; ws += (size_t)(N + 1) * sizeof(int);
    int* bsum     = (int*)ws; ws += 64 * sizeof(int);
    int* slot     = (int*)ws; ws += (size_t)E * sizeof(int);
    ws = (char*)(((size_t)ws + 15) & ~(size_t)15);
    float4* meta  = (float4*)ws; ws += (size_t)E * sizeof(float4);

    hipMemsetAsync(deg, 0, (size_t)(N + 1) * sizeof(int), stream);

    int nDeg = (E + 255) / 256;
    k_deg_wt<<<nDeg + 128, 256, 0, stream>>>(rows, deg, slot, E, nDeg, W0, W1, Bt);

    int nb = (N + 1023) >> 10;  // 49 for N=50000
    k_scan1<<<nb, 1024, 0, stream>>>(deg, rowptr, bsum, N);

    int nsc = (N + 256) / 256;  // blocks covering indices 0..N inclusive
    dim3 gg(Npad / 64, 3);      // y=0: zj (x<ceil(N/128)), y=1: mfma, y=2: scan-finalize
    k_fused<<<gg, 256, 0, stream>>>(feat, Wp, Bt, b0, b1, att, Wg,
                                    h0, hb, zj, gpart, fdotg, a_self, a_neigh,
                                    rowptr, bsum, nb, nsc, N);

    k_scatter_meta<<<nDeg, 256, 0, stream>>>(rows, cols, vals, rowptr, slot,
                                             a_neigh, fdotg, meta, E);

    int nb4 = (N + 3) / 4;
    k_aggregate<<<nb4, 256, 0, stream>>>(meta, rowptr, h0, hb, zj,
                                         a_self, gpart, Wg,
                                         scale0, offset0, scale1, offset1, out, N, E);
}

// Round 10
// 257.091 us; speedup vs baseline: 1.0327x; 1.0327x over previous
//
#include <hip/hip_runtime.h>

#define DIN 128
#define DG 64

typedef __attribute__((ext_vector_type(8))) short short8;
typedef __attribute__((ext_vector_type(4))) float f32x4;

// ---- bf16 helpers (RNE) ----
static __device__ __forceinline__ unsigned short f2bf(float x) {
    unsigned u = __builtin_bit_cast(unsigned, x);
    u = (u + 0x7FFF + ((u >> 16) & 1)) >> 16;
    return (unsigned short)u;
}
static __device__ __forceinline__ float bf2f(unsigned short s) {
    return __builtin_bit_cast(float, (unsigned)s << 16);
}

// ---------- K1: degree+slot capture, fused with W0|W1 -> Bt transpose ----------
__global__ void k_deg_wt(const int* __restrict__ rows, int* __restrict__ deg,
                         int* __restrict__ slot, int E, int nDeg,
                         const float* __restrict__ W0, const float* __restrict__ W1,
                         unsigned short* __restrict__ Bt) {
    int b = blockIdx.x;
    if (b < nDeg) {
        int e = b * 256 + threadIdx.x;
        if (e < E) slot[e] = atomicAdd(&deg[rows[e]], 1);
    } else {
        int k = b - nDeg;  // 0..127
        int c = threadIdx.x;
        const float* W = (c < 128) ? W0 : W1;
        Bt[c * 128 + k] = f2bf(W[k * 128 + (c & 127)]);
    }
}

// ---------- K2: per-block exclusive scan (1024 elems/block) ----------
__global__ __launch_bounds__(1024) void k_scan1(const int* __restrict__ deg,
                                                int* __restrict__ rowptr,
                                                int* __restrict__ bsum, int n) {
    __shared__ int wsum[16];
    __shared__ int woff[16];
    int tid = threadIdx.x;
    int lane = tid & 63, w = tid >> 6;
    int i = blockIdx.x * 1024 + tid;
    int v = (i < n) ? deg[i] : 0;
    int x = v;
    #pragma unroll
    for (int off = 1; off < 64; off <<= 1) {
        int y = __shfl_up(x, off, 64);
        if (lane >= off) x += y;
    }
    if (lane == 63) wsum[w] = x;
    __syncthreads();
    if (w == 0) {
        int t = (lane < 16) ? wsum[lane] : 0;
        int xx = t;
        #pragma unroll
        for (int off = 1; off < 16; off <<= 1) {
            int y = __shfl_up(xx, off, 64);
            if (lane >= off) xx += y;
        }
        if (lane < 16) woff[lane] = xx - t;  // exclusive
    }
    __syncthreads();
    if (i < n) rowptr[i] = x - v + woff[w];
    if (tid == 1023) bsum[blockIdx.x] = woff[15] + wsum[15];
}

// ---------- K4: fused big kernel ----------
// y==0 : zj = feat @ Wp (f32, gate-critical) + gpart/fdotg dots
// y==1 : h0 (f32) + h1 (bf16) via 16x16x32 bf16 MFMA + a_self/a_neigh
// y==2 : scan finalize (add bsum prefix to rowptr; write rowptr[n])
#define AS_LD 132
#define ALD 136
#define SMEM_BYTES 25088  // max(32*132*4 + 32*64*4, 64*136*2 + 1024)

static __device__ __forceinline__ void zj_body(
    const float* __restrict__ feat, const float* __restrict__ Wp,
    const float* __restrict__ Wg,
    float* __restrict__ zj, float* __restrict__ gpart, float* __restrict__ fdotg,
    int N, char* smem) {
    float* As = (float*)smem;
    float* Bs = (float*)(smem + 32 * AS_LD * 4);
    int tid = threadIdx.x;
    int tx = tid & 15, ty = tid >> 4;
    int m0 = blockIdx.x * 128;
    if (m0 >= N) return;
    float acc[8][4];
    #pragma unroll
    for (int r = 0; r < 8; ++r)
        #pragma unroll
        for (int c = 0; c < 4; ++c) acc[r][c] = 0.f;
    float gdot[8], fdot[8];
    #pragma unroll
    for (int r = 0; r < 8; ++r) { gdot[r] = 0.f; fdot[r] = 0.f; }
    for (int kc = 0; kc < 128; kc += 32) {
        for (int i = tid; i < 1024; i += 256) {
            int m = i >> 3, kq = (i & 7) << 2;
            int node = m0 + m;
            float4 f;
            if (node < N) f = *(const float4*)&feat[(size_t)node * 128 + kc + kq];
            else          f = make_float4(0.f, 0.f, 0.f, 0.f);
            As[(kq + 0) * AS_LD + m] = f.x;
            As[(kq + 1) * AS_LD + m] = f.y;
            As[(kq + 2) * AS_LD + m] = f.z;
            As[(kq + 3) * AS_LD + m] = f.w;
        }
        for (int i = tid; i < 512; i += 256) {
            int k = i >> 4, cq = (i & 15) << 2;
            *(float4*)&Bs[k * 64 + cq] = *(const float4*)&Wp[(size_t)(kc + k) * 64 + cq];
        }
        __syncthreads();
        #pragma unroll 8
        for (int kk = 0; kk < 32; ++kk) {
            const float* ar = &As[kk * AS_LD];
            float4 a0 = *(const float4*)(ar + 4 * tx);
            float4 a1 = *(const float4*)(ar + 64 + 4 * tx);
            float4 b0v = *(const float4*)&Bs[kk * 64 + 4 * ty];
            float a[8] = {a0.x, a0.y, a0.z, a0.w, a1.x, a1.y, a1.z, a1.w};
            #pragma unroll
            for (int r = 0; r < 8; ++r) {
                acc[r][0] += a[r] * b0v.x; acc[r][1] += a[r] * b0v.y;
                acc[r][2] += a[r] * b0v.z; acc[r][3] += a[r] * b0v.w;
            }
            float g1 = Wg[kc + kk];        // Wg[0:128]   -> gpart
            float g2 = Wg[192 + kc + kk];  // Wg[192:320] -> fdotg
            #pragma unroll
            for (int r = 0; r < 8; ++r) { gdot[r] += a[r] * g1; fdot[r] += a[r] * g2; }
        }
        __syncthreads();
    }
    #pragma unroll
    for (int r = 0; r < 8; ++r) {
        int node = m0 + ((r < 4) ? (4 * tx + r) : (64 + 4 * tx + (r - 4)));
        if (node >= N) continue;
        *(float4*)&zj[(size_t)node * 64 + 4 * ty] =
            make_float4(acc[r][0], acc[r][1], acc[r][2], acc[r][3]);
        if (ty == 0) { gpart[node] = gdot[r]; fdotg[node] = fdot[r]; }
    }
}

static __device__ __forceinline__ void mfma_body(
    const float* __restrict__ feat, const unsigned short* __restrict__ Bt,
    const float* __restrict__ b0, const float* __restrict__ b1,
    const float* __restrict__ att,
    float* __restrict__ h0, unsigned short* __restrict__ hb,
    float* __restrict__ a_self, float* __restrict__ a_neigh, int N, char* smem) {
    unsigned short* As = (unsigned short*)smem;
    float* sredA = (float*)(smem + 64 * ALD * 2);
    float* nredA = sredA + 128;
    int tid = threadIdx.x;
    int m0 = blockIdx.x * 64;
    // stage A: 64 rows x 128 k, f32 -> bf16 inline (32 float4-chunks/row)
    for (int i = tid; i < 2048; i += 256) {
        int row = i >> 5, ch = i & 31;
        int node = m0 + row;
        float4 f;
        if (node < N) f = *(const float4*)&feat[(size_t)node * 128 + ch * 4];
        else          f = make_float4(0.f, 0.f, 0.f, 0.f);
        unsigned p0 = (unsigned)f2bf(f.x) | ((unsigned)f2bf(f.y) << 16);
        unsigned p1 = (unsigned)f2bf(f.z) | ((unsigned)f2bf(f.w) << 16);
        *(uint2*)&As[row * ALD + ch * 4] = make_uint2(p0, p1);
    }
    __syncthreads();
    int w = tid >> 6, lane = tid & 63;
    int lm = lane & 15, q = lane >> 4;
    f32x4 acc[4][4];  // [row-tile][col-tile]
    #pragma unroll
    for (int rt = 0; rt < 4; ++rt)
        #pragma unroll
        for (int ct = 0; ct < 4; ++ct)
            #pragma unroll
            for (int r = 0; r < 4; ++r) acc[rt][ct][r] = 0.f;
    #pragma unroll
    for (int ks = 0; ks < 4; ++ks) {
        short8 a[4], b[4];
        #pragma unroll
        for (int rt = 0; rt < 4; ++rt)
            a[rt] = *(const short8*)&As[(rt * 16 + lm) * ALD + ks * 32 + q * 8];
        #pragma unroll
        for (int ct = 0; ct < 4; ++ct)
            b[ct] = *(const short8*)&Bt[(size_t)(w * 64 + ct * 16 + lm) * 128 + ks * 32 + q * 8];
        #pragma unroll
        for (int rt = 0; rt < 4; ++rt)
            #pragma unroll
            for (int ct = 0; ct < 4; ++ct)
                acc[rt][ct] = __builtin_amdgcn_mfma_f32_16x16x32_bf16(a[rt], b[ct], acc[rt][ct], 0, 0, 0);
    }
    // epilogue: bias + relu, store, att-dot partials
    float sacc[4][4];
    #pragma unroll
    for (int rt = 0; rt < 4; ++rt)
        #pragma unroll
        for (int r = 0; r < 4; ++r) sacc[rt][r] = 0.f;
    #pragma unroll
    for (int ct = 0; ct < 4; ++ct) {
        int col = w * 64 + ct * 16 + lm;  // 0..255, wave-uniform half
        float attc = att[col];
        float bias = (w < 2) ? b0[col] : b1[col - 128];
        #pragma unroll
        for (int rt = 0; rt < 4; ++rt) {
            #pragma unroll
            for (int r = 0; r < 4; ++r) {
                float v = acc[rt][ct][r] + bias;
                v = fmaxf(v, 0.f);
                sacc[rt][r] += v * attc;
                int node = m0 + rt * 16 + q * 4 + r;
                if (node < N) {
                    if (w < 2) h0[(size_t)node * 128 + col] = v;
                    else       hb[(size_t)node * 128 + (col - 128)] = f2bf(v);
                }
            }
        }
    }
    float* red = (w < 2) ? sredA : nredA;
    #pragma unroll
    for (int rt = 0; rt < 4; ++rt)
        #pragma unroll
        for (int r = 0; r < 4; ++r) {
            float s = sacc[rt][r];
            s += __shfl_xor(s, 1, 64); s += __shfl_xor(s, 2, 64);
            s += __shfl_xor(s, 4, 64); s += __shfl_xor(s, 8, 64);
            if (lm == 0) red[(w & 1) * 64 + rt * 16 + q * 4 + r] = s;
        }
    __syncthreads();
    if (tid < 64) {
        int node = m0 + tid;
        if (node < N) {
            float s  = sredA[tid] + sredA[64 + tid];
            float nn = nredA[tid] + nredA[64 + tid];
            a_self[node]  = (s  >= 0.f) ? s  : 0.2f * s;
            a_neigh[node] = (nn >= 0.f) ? nn : 0.2f * nn;
        }
    }
}

static __device__ __forceinline__ void scanfin_body(
    int* __restrict__ rowptr, const int* __restrict__ bsum, int nbs, int n) {
    int b = blockIdx.x;
    int i = b * 256 + threadIdx.x;
    if (b * 256 > n) return;
    int seg = (b * 256) >> 10;  // block lies entirely in one 1024-segment
    int pref = 0;
    for (int t = 0; t < seg; ++t) pref += bsum[t];
    if (i < n) rowptr[i] += pref;
    else if (i == n) {
        int tot = pref;
        for (int t = seg; t < nbs; ++t) tot += bsum[t];
        rowptr[n] = tot;
    }
}

__global__ __launch_bounds__(256) void k_fused(
    const float* __restrict__ feat, const float* __restrict__ Wp,
    const unsigned short* __restrict__ Bt,
    const float* __restrict__ b0, const float* __restrict__ b1,
    const float* __restrict__ att, const float* __restrict__ Wg,
    float* __restrict__ h0, unsigned short* __restrict__ hb,
    float* __restrict__ zj, float* __restrict__ gpart, float* __restrict__ fdotg,
    float* __restrict__ a_self, float* __restrict__ a_neigh,
    int* __restrict__ rowptr, const int* __restrict__ bsum, int nbs, int nsc, int N) {
    __shared__ __align__(16) char smem[SMEM_BYTES];
    if (blockIdx.y == 0)
        zj_body(feat, Wp, Wg, zj, gpart, fdotg, N, smem);
    else if (blockIdx.y == 1)
        mfma_body(feat, Bt, b0, b1, att, h0, hb, a_self, a_neigh, N, smem);
    else if (blockIdx.x < nsc)
        scanfin_body(rowptr, bsum, nbs, N);
}

// ---------- K5: scatter final edge meta into CSR slot ----------
__global__ void k_scatter_meta(const int* __restrict__ rows, const int* __restrict__ cols,
                               const float* __restrict__ vals,
                               const int* __restrict__ rowptr, const int* __restrict__ slot,
                               const float* __restrict__ a_neigh, const float* __restrict__ fdotg,
                               float4* __restrict__ meta, int E) {
    int e = blockIdx.x * blockDim.x + threadIdx.x;
    if (e < E) {
        int c = cols[e];
        int dst = rowptr[rows[e]] + slot[e];
        meta[dst] = make_float4(__builtin_bit_cast(float, c),
                                a_neigh[c], vals[e] * fdotg[c], 0.f);
    }
}

// ---------- K6: per-row CSR aggregation, two waves per row ----------
// R9 lesson: 16-deep batch -> VGPR 72 -> occupancy 27% (cliff). Keep C=8 (VGPR ~32)
// and double in-flight gathers via a second wave per row, LDS-combined.
template<int C>
static __device__ __forceinline__ void agg_chunk_m(
    const float4* __restrict__ meta, int j, int je, int E, int lane, float asr,
    const unsigned short* __restrict__ hb, const float* __restrict__ zj,
    float2& acca, float& zmax, float& vfsum) {
    float4 m[C]; bool act[C];
    #pragma unroll
    for (int t = 0; t < C; ++t) {
        int jj = j + t;
        act[t] = jj < je;
        m[t] = meta[min(jj, E - 1)];
    }
    ushort2 hv[C]; float zv[C];
    #pragma unroll
    for (int t = 0; t < C; ++t) {
        int c = __builtin_bit_cast(int, m[t].x);
        hv[t] = ((const ushort2*)(hb + (size_t)c * 128))[lane];
        zv[t] = zj[(size_t)c * 64 + lane];
    }
    #pragma unroll
    for (int t = 0; t < C; ++t) {
        float es = act[t] ? (asr + m[t].y) : 0.f;
        acca.x += es * bf2f(hv[t].x);
        acca.y += es * bf2f(hv[t].y);
        zmax = fmaxf(zmax, act[t] ? zv[t] : -__builtin_inff());
        vfsum += act[t] ? m[t].z : 0.f;
    }
}

__global__ __launch_bounds__(256) void k_aggregate(
    const float4* __restrict__ meta, const int* __restrict__ rowptr,
    const float* __restrict__ h0, const unsigned short* __restrict__ hb,
    const float* __restrict__ zj,
    const float* __restrict__ a_self, const float* __restrict__ gpart,
    const float* __restrict__ Wg,
    const float* __restrict__ scale0, const float* __restrict__ offset0,
    const float* __restrict__ scale1, const float* __restrict__ offset1,
    float* __restrict__ out, int N, int E) {
    __shared__ float ls[2][2][256];  // [rowInBlock][wave][lane*4]: acca.x,.y,zmax,vfsum
    int tid = threadIdx.x;
    int pr = tid >> 7;          // row within block (2 rows/block)
    int h  = (tid >> 6) & 1;    // wave within row
    int lane = tid & 63;
    int r = blockIdx.x * 2 + pr;
    bool valid = r < N;
    int jb = 0, je = 0;
    float asr = 0.f;
    if (valid) { jb = rowptr[r]; je = rowptr[r + 1]; asr = a_self[r]; }
    float2 acca = {0.f, 0.f};
    float zmax = -__builtin_inff();
    float vfsum = 0.f;
    for (int j = jb + 8 * h; j < je; j += 16)
        agg_chunk_m<8>(meta, j, je, E, lane, asr, hb, zj, acca, zmax, vfsum);
    *(float4*)&ls[pr][h][lane * 4] = make_float4(acca.x, acca.y, zmax, vfsum);
    __syncthreads();
    if (h == 1 || !valid) return;
    float4 o1 = *(const float4*)&ls[pr][1][lane * 4];
    acca.x += o1.x; acca.y += o1.y;
    zmax = fmaxf(zmax, o1.z);
    vfsum += o1.w;
    if (jb == je) zmax = 0.f;  // empty segment: -inf -> 0
    float gs = zmax * Wg[128 + lane];
    #pragma unroll
    for (int off = 32; off; off >>= 1) gs += __shfl_xor(gs, off, 64);
    float gate = gpart[r] + gs + vfsum;  // all-f32 gate path (sign matters)
    float2 ag = {acca.x * gate, acca.y * gate};
    // BN on h0 row
    float2 x0 = ((const float2*)(h0 + (size_t)r * 128))[lane];
    float m0s = x0.x + x0.y;
    #pragma unroll
    for (int off = 32; off; off >>= 1) m0s += __shfl_xor(m0s, off, 64);
    float m0 = m0s * (1.f / 128.f);
    float d0x = x0.x - m0, d0y = x0.y - m0;
    float v0s = d0x * d0x + d0y * d0y;
    #pragma unroll
    for (int off = 32; off; off >>= 1) v0s += __shfl_xor(v0s, off, 64);
    float inv0 = rsqrtf(v0s * (1.f / 128.f) + 1e-9f);
    // BN on gated aggregation
    float m1s = ag.x + ag.y;
    #pragma unroll
    for (int off = 32; off; off >>= 1) m1s += __shfl_xor(m1s, off, 64);
    float m1 = m1s * (1.f / 128.f);
    float d1x = ag.x - m1, d1y = ag.y - m1;
    float v1s = d1x * d1x + d1y * d1y;
    #pragma unroll
    for (int off = 32; off; off >>= 1) v1s += __shfl_xor(v1s, off, 64);
    float inv1 = rsqrtf(v1s * (1.f / 128.f) + 1e-9f);
    float2 sc0 = ((const float2*)scale0)[lane], of0 = ((const float2*)offset0)[lane];
    float2 sc1 = ((const float2*)scale1)[lane], of1 = ((const float2*)offset1)[lane];
    float2 o;
    o.x = d0x * sc0.x * inv0 + of0.x + d1x * sc1.x * inv1 + of1.x;
    o.y = d0y * sc0.y * inv0 + of0.y + d1y * sc1.y * inv1 + of1.y;
    ((float2*)(out + (size_t)r * 128))[lane] = o;
}

extern "C" void kernel_launch(void* const* d_in, const int* in_sizes, int n_in,
                              void* d_out, int out_size, void* d_ws, size_t ws_size,
                              hipStream_t stream) {
    const int*   rows   = (const int*)d_in[0];
    const int*   cols   = (const int*)d_in[1];
    const float* vals   = (const float*)d_in[2];
    const float* feat   = (const float*)d_in[3];
    const float* W0     = (const float*)d_in[4];
    const float* b0     = (const float*)d_in[5];
    const float* W1     = (const float*)d_in[6];
    const float* b1     = (const float*)d_in[7];
    const float* att    = (const float*)d_in[8];
    const float* Wp     = (const float*)d_in[9];
    const float* Wg     = (const float*)d_in[10];
    const float* offset0 = (const float*)d_in[11];
    const float* scale0  = (const float*)d_in[12];
    const float* offset1 = (const float*)d_in[13];
    const float* scale1  = (const float*)d_in[14];
    float* out = (float*)d_out;

    const int E = in_sizes[0];
    const int N = in_sizes[3] / DIN;
    const int Npad = (N + 63) & ~63;

    char* ws = (char*)d_ws;
    float* h0          = (float*)ws;          ws += (size_t)N * 128 * sizeof(float);
    unsigned short* hb = (unsigned short*)ws; ws += (size_t)N * 128 * sizeof(unsigned short);
    float* zj          = (float*)ws;          ws += (size_t)N * 64 * sizeof(float);
    unsigned short* Bt = (unsigned short*)ws; ws += (size_t)256 * 128 * sizeof(unsigned short);
    float* a_self  = (float*)ws; ws += (size_t)N * sizeof(float);
    float* a_neigh = (float*)ws; ws += (size_t)N * sizeof(float);
    float* gpart   = (float*)ws; ws += (size_t)N * sizeof(float);
    float* fdotg   = (float*)ws; ws += (size_t)N * sizeof(float);
    int* deg      = (int*)ws; ws += (size_t)(N + 1) * sizeof(int);
    int* rowptr   = (int*)ws; ws += (size_t)(N + 1) * sizeof(int);
    int* bsum     = (int*)ws; ws += 64 * sizeof(int);
    int* slot     = (int*)ws; ws += (size_t)E * sizeof(int);
    ws = (char*)(((size_t)ws + 15) & ~(size_t)15);
    float4* meta  = (float4*)ws; ws += (size_t)E * sizeof(float4);

    hipMemsetAsync(deg, 0, (size_t)(N + 1) * sizeof(int), stream);

    int nDeg = (E + 255) / 256;
    k_deg_wt<<<nDeg + 128, 256, 0, stream>>>(rows, deg, slot, E, nDeg, W0, W1, Bt);

    int nb = (N + 1023) >> 10;  // 49 for N=50000
    k_scan1<<<nb, 1024, 0, stream>>>(deg, rowptr, bsum, N);

    int nsc = (N + 256) / 256;  // blocks covering indices 0..N inclusive
    dim3 gg(Npad / 64, 3);      // y=0: zj (x<ceil(N/128)), y=1: mfma, y=2: scan-finalize
    k_fused<<<gg, 256, 0, stream>>>(feat, Wp, Bt, b0, b1, att, Wg,
                                    h0, hb, zj, gpart, fdotg, a_self, a_neigh,
                                    rowptr, bsum, nb, nsc, N);

    k_scatter_meta<<<nDeg, 256, 0, stream>>>(rows, cols, vals, rowptr, slot,
                                             a_neigh, fdotg, meta, E);

    int nb2 = (N + 1) / 2;  // 2 rows/block, 2 waves/row
    k_aggregate<<<nb2, 256, 0, stream>>>(meta, rowptr, h0, hb, zj,
                                         a_self, gpart, Wg,
                                         scale0, offset0, scale1, offset1, out, N, E);
}

// Round 11
// 248.783 us; speedup vs baseline: 1.0671x; 1.0334x over previous
//
#include <hip/hip_runtime.h>

#define DIN 128
#define DG 64

typedef __attribute__((ext_vector_type(8))) short short8;
typedef __attribute__((ext_vector_type(4))) float f32x4;

// ---- bf16 helpers (RNE) ----
static __device__ __forceinline__ unsigned short f2bf(float x) {
    unsigned u = __builtin_bit_cast(unsigned, x);
    u = (u + 0x7FFF + ((u >> 16) & 1)) >> 16;
    return (unsigned short)u;
}
static __device__ __forceinline__ float bf2f(unsigned short s) {
    return __builtin_bit_cast(float, (unsigned)s << 16);
}

// ---------- K1: degree+slot capture, fused with W0|W1 -> Bt transpose ----------
__global__ void k_pre(const int* __restrict__ rows, int* __restrict__ deg,
                      int* __restrict__ slot, int E, int nDeg,
                      const float* __restrict__ W0, const float* __restrict__ W1,
                      unsigned short* __restrict__ Bt) {
    int b = blockIdx.x;
    if (b < nDeg) {
        int e = b * 256 + threadIdx.x;
        if (e < E) slot[e] = atomicAdd(&deg[rows[e]], 1);
    } else {
        int k = b - nDeg;  // 0..127
        int c = threadIdx.x;
        const float* W = (c < 128) ? W0 : W1;
        Bt[c * 128 + k] = f2bf(W[k * 128 + (c & 127)]);
    }
}

// ---------- K2 roles, fused into one kernel ----------
// y==0 : zj = feat @ Wp (f32, gate-critical) + gpart/fdotg dots
// y==1 : h0 (f32) + h1 (bf16) via 16x16x32 bf16 MFMA + a_self/a_neigh
// y==2 : full exclusive scan deg -> rowptr via decoupled lookback (x < nbs)
#define AS_LD 132
#define ALD 136
#define SMEM_BYTES 25088  // max(32*132*4 + 32*64*4, 64*136*2 + 1024)

static __device__ __forceinline__ void zj_body(
    const float* __restrict__ feat, const float* __restrict__ Wp,
    const float* __restrict__ Wg,
    float* __restrict__ zj, float* __restrict__ gpart, float* __restrict__ fdotg,
    int N, char* smem) {
    float* As = (float*)smem;
    float* Bs = (float*)(smem + 32 * AS_LD * 4);
    int tid = threadIdx.x;
    int tx = tid & 15, ty = tid >> 4;
    int m0 = blockIdx.x * 128;
    if (m0 >= N) return;
    float acc[8][4];
    #pragma unroll
    for (int r = 0; r < 8; ++r)
        #pragma unroll
        for (int c = 0; c < 4; ++c) acc[r][c] = 0.f;
    float gdot[8], fdot[8];
    #pragma unroll
    for (int r = 0; r < 8; ++r) { gdot[r] = 0.f; fdot[r] = 0.f; }
    for (int kc = 0; kc < 128; kc += 32) {
        for (int i = tid; i < 1024; i += 256) {
            int m = i >> 3, kq = (i & 7) << 2;
            int node = m0 + m;
            float4 f;
            if (node < N) f = *(const float4*)&feat[(size_t)node * 128 + kc + kq];
            else          f = make_float4(0.f, 0.f, 0.f, 0.f);
            As[(kq + 0) * AS_LD + m] = f.x;
            As[(kq + 1) * AS_LD + m] = f.y;
            As[(kq + 2) * AS_LD + m] = f.z;
            As[(kq + 3) * AS_LD + m] = f.w;
        }
        for (int i = tid; i < 512; i += 256) {
            int k = i >> 4, cq = (i & 15) << 2;
            *(float4*)&Bs[k * 64 + cq] = *(const float4*)&Wp[(size_t)(kc + k) * 64 + cq];
        }
        __syncthreads();
        #pragma unroll 8
        for (int kk = 0; kk < 32; ++kk) {
            const float* ar = &As[kk * AS_LD];
            float4 a0 = *(const float4*)(ar + 4 * tx);
            float4 a1 = *(const float4*)(ar + 64 + 4 * tx);
            float4 b0v = *(const float4*)&Bs[kk * 64 + 4 * ty];
            float a[8] = {a0.x, a0.y, a0.z, a0.w, a1.x, a1.y, a1.z, a1.w};
            #pragma unroll
            for (int r = 0; r < 8; ++r) {
                acc[r][0] += a[r] * b0v.x; acc[r][1] += a[r] * b0v.y;
                acc[r][2] += a[r] * b0v.z; acc[r][3] += a[r] * b0v.w;
            }
            float g1 = Wg[kc + kk];        // Wg[0:128]   -> gpart
            float g2 = Wg[192 + kc + kk];  // Wg[192:320] -> fdotg
            #pragma unroll
            for (int r = 0; r < 8; ++r) { gdot[r] += a[r] * g1; fdot[r] += a[r] * g2; }
        }
        __syncthreads();
    }
    #pragma unroll
    for (int r = 0; r < 8; ++r) {
        int node = m0 + ((r < 4) ? (4 * tx + r) : (64 + 4 * tx + (r - 4)));
        if (node >= N) continue;
        *(float4*)&zj[(size_t)node * 64 + 4 * ty] =
            make_float4(acc[r][0], acc[r][1], acc[r][2], acc[r][3]);
        if (ty == 0) { gpart[node] = gdot[r]; fdotg[node] = fdot[r]; }
    }
}

static __device__ __forceinline__ void mfma_body(
    const float* __restrict__ feat, const unsigned short* __restrict__ Bt,
    const float* __restrict__ b0, const float* __restrict__ b1,
    const float* __restrict__ att,
    float* __restrict__ h0, unsigned short* __restrict__ hb,
    float* __restrict__ a_self, float* __restrict__ a_neigh, int N, char* smem) {
    unsigned short* As = (unsigned short*)smem;
    float* sredA = (float*)(smem + 64 * ALD * 2);
    float* nredA = sredA + 128;
    int tid = threadIdx.x;
    int m0 = blockIdx.x * 64;
    // stage A: 64 rows x 128 k, f32 -> bf16 inline (32 float4-chunks/row)
    for (int i = tid; i < 2048; i += 256) {
        int row = i >> 5, ch = i & 31;
        int node = m0 + row;
        float4 f;
        if (node < N) f = *(const float4*)&feat[(size_t)node * 128 + ch * 4];
        else          f = make_float4(0.f, 0.f, 0.f, 0.f);
        unsigned p0 = (unsigned)f2bf(f.x) | ((unsigned)f2bf(f.y) << 16);
        unsigned p1 = (unsigned)f2bf(f.z) | ((unsigned)f2bf(f.w) << 16);
        *(uint2*)&As[row * ALD + ch * 4] = make_uint2(p0, p1);
    }
    __syncthreads();
    int w = tid >> 6, lane = tid & 63;
    int lm = lane & 15, q = lane >> 4;
    f32x4 acc[4][4];  // [row-tile][col-tile]
    #pragma unroll
    for (int rt = 0; rt < 4; ++rt)
        #pragma unroll
        for (int ct = 0; ct < 4; ++ct)
            #pragma unroll
            for (int r = 0; r < 4; ++r) acc[rt][ct][r] = 0.f;
    #pragma unroll
    for (int ks = 0; ks < 4; ++ks) {
        short8 a[4], b[4];
        #pragma unroll
        for (int rt = 0; rt < 4; ++rt)
            a[rt] = *(const short8*)&As[(rt * 16 + lm) * ALD + ks * 32 + q * 8];
        #pragma unroll
        for (int ct = 0; ct < 4; ++ct)
            b[ct] = *(const short8*)&Bt[(size_t)(w * 64 + ct * 16 + lm) * 128 + ks * 32 + q * 8];
        #pragma unroll
        for (int rt = 0; rt < 4; ++rt)
            #pragma unroll
            for (int ct = 0; ct < 4; ++ct)
                acc[rt][ct] = __builtin_amdgcn_mfma_f32_16x16x32_bf16(a[rt], b[ct], acc[rt][ct], 0, 0, 0);
    }
    // epilogue: bias + relu, store, att-dot partials
    float sacc[4][4];
    #pragma unroll
    for (int rt = 0; rt < 4; ++rt)
        #pragma unroll
        for (int r = 0; r < 4; ++r) sacc[rt][r] = 0.f;
    #pragma unroll
    for (int ct = 0; ct < 4; ++ct) {
        int col = w * 64 + ct * 16 + lm;  // 0..255, wave-uniform half
        float attc = att[col];
        float bias = (w < 2) ? b0[col] : b1[col - 128];
        #pragma unroll
        for (int rt = 0; rt < 4; ++rt) {
            #pragma unroll
            for (int r = 0; r < 4; ++r) {
                float v = acc[rt][ct][r] + bias;
                v = fmaxf(v, 0.f);
                sacc[rt][r] += v * attc;
                int node = m0 + rt * 16 + q * 4 + r;
                if (node < N) {
                    if (w < 2) h0[(size_t)node * 128 + col] = v;
                    else       hb[(size_t)node * 128 + (col - 128)] = f2bf(v);
                }
            }
        }
    }
    float* red = (w < 2) ? sredA : nredA;
    #pragma unroll
    for (int rt = 0; rt < 4; ++rt)
        #pragma unroll
        for (int r = 0; r < 4; ++r) {
            float s = sacc[rt][r];
            s += __shfl_xor(s, 1, 64); s += __shfl_xor(s, 2, 64);
            s += __shfl_xor(s, 4, 64); s += __shfl_xor(s, 8, 64);
            if (lm == 0) red[(w & 1) * 64 + rt * 16 + q * 4 + r] = s;
        }
    __syncthreads();
    if (tid < 64) {
        int node = m0 + tid;
        if (node < N) {
            float s  = sredA[tid] + sredA[64 + tid];
            float nn = nredA[tid] + nredA[64 + tid];
            a_self[node]  = (s  >= 0.f) ? s  : 0.2f * s;
            a_neigh[node] = (nn >= 0.f) ? nn : 0.2f * nn;
        }
    }
}

// decoupled-lookback exclusive scan: 256 thr/block, 1024 elems/block (4/thread)
// bstate[b] = (flag<<32)|value; flag 1 = aggregate ready, 2 = inclusive prefix ready
static __device__ __forceinline__ void scan_body(
    const int* __restrict__ deg, int* __restrict__ rowptr,
    unsigned long long* __restrict__ bstate, int n, int nbs, char* smem) {
    int b = blockIdx.x;
    if (b >= nbs) return;
    int* wsum = (int*)smem;        // [4]
    int* bprefs = (int*)smem + 8;  // [1]
    int tid = threadIdx.x, lane = tid & 63, w = tid >> 6;
    int base = b * 1024 + tid * 4;
    int4 v = make_int4(0, 0, 0, 0);
    if (base + 3 < n) v = *(const int4*)&deg[base];
    else {
        if (base     < n) v.x = deg[base];
        if (base + 1 < n) v.y = deg[base + 1];
        if (base + 2 < n) v.z = deg[base + 2];
        if (base + 3 < n) v.w = deg[base + 3];
    }
    int s = v.x + v.y + v.z + v.w;
    int x = s;
    #pragma unroll
    for (int off = 1; off < 64; off <<= 1) {
        int y = __shfl_up(x, off, 64);
        if (lane >= off) x += y;
    }
    if (lane == 63) wsum[w] = x;
    __syncthreads();
    int wpref = 0;
    for (int t = 0; t < w; ++t) wpref += wsum[t];
    int btotal = wsum[0] + wsum[1] + wsum[2] + wsum[3];
    int excl = x - s + wpref;  // exclusive prefix within block of this thread's quad
    if (tid == 0) {
        unsigned long long pack =
            ((unsigned long long)(b == 0 ? 2u : 1u) << 32) | (unsigned)btotal;
        atomicExch(&bstate[b], pack);
        int pref = 0;
        if (b > 0) {
            int i = b - 1;
            while (i >= 0) {
                unsigned long long st = atomicAdd(&bstate[i], 0ULL);
                unsigned f = (unsigned)(st >> 32);
                if (f == 0) { __builtin_amdgcn_s_sleep(1); continue; }
                pref += (int)(st & 0xffffffffULL);
                if (f == 2) break;
                --i;
            }
            atomicExch(&bstate[b], (2ULL << 32) | (unsigned)(pref + btotal));
        }
        bprefs[0] = pref;
    }
    __syncthreads();
    int p = bprefs[0] + excl;
    if (base + 3 < n) {
        *(int4*)&rowptr[base] = make_int4(p, p + v.x, p + v.x + v.y, p + v.x + v.y + v.z);
    } else {
        if (base     < n) rowptr[base]     = p;
        if (base + 1 < n) rowptr[base + 1] = p + v.x;
        if (base + 2 < n) rowptr[base + 2] = p + v.x + v.y;
        if (base + 3 < n) rowptr[base + 3] = p + v.x + v.y + v.z;
    }
    if (b == nbs - 1 && tid == 0) rowptr[n] = bprefs[0] + btotal;
}

__global__ __launch_bounds__(256) void k_fused(
    const float* __restrict__ feat, const float* __restrict__ Wp,
    const unsigned short* __restrict__ Bt,
    const float* __restrict__ b0, const float* __restrict__ b1,
    const float* __restrict__ att, const float* __restrict__ Wg,
    float* __restrict__ h0, unsigned short* __restrict__ hb,
    float* __restrict__ zj, float* __restrict__ gpart, float* __restrict__ fdotg,
    float* __restrict__ a_self, float* __restrict__ a_neigh,
    const int* __restrict__ deg, int* __restrict__ rowptr,
    unsigned long long* __restrict__ bstate, int nbs, int N) {
    __shared__ __align__(16) char smem[SMEM_BYTES];
    if (blockIdx.y == 0)
        zj_body(feat, Wp, Wg, zj, gpart, fdotg, N, smem);
    else if (blockIdx.y == 1)
        mfma_body(feat, Bt, b0, b1, att, h0, hb, a_self, a_neigh, N, smem);
    else
        scan_body(deg, rowptr, bstate, N, nbs, smem);
}

// ---------- K3: scatter final edge meta into CSR slot ----------
__global__ void k_scatter_meta(const int* __restrict__ rows, const int* __restrict__ cols,
                               const float* __restrict__ vals,
                               const int* __restrict__ rowptr, const int* __restrict__ slot,
                               const float* __restrict__ a_neigh, const float* __restrict__ fdotg,
                               float4* __restrict__ meta, int E) {
    int e = blockIdx.x * blockDim.x + threadIdx.x;
    if (e < E) {
        int c = cols[e];
        int dst = rowptr[rows[e]] + slot[e];
        meta[dst] = make_float4(__builtin_bit_cast(float, c),
                                a_neigh[c], vals[e] * fdotg[c], 0.f);
    }
}

// ---------- K4: per-row CSR aggregation (R8 shape: 1 wave/row, C=8) ----------
// R9/R10 lessons: 16-deep batch -> VGPR cliff (72 regs, 27% occ); foreign-row
// clamp (E-1) -> +20MB fetch. Clamp to own row's last edge (L1-hot), C=8.
template<int C>
static __device__ __forceinline__ void agg_chunk_m(
    const float4* __restrict__ meta, int j, int je, int lane, float asr,
    const unsigned short* __restrict__ hb, const float* __restrict__ zj,
    float2& acca, float& zmax, float& vfsum) {
    int jclamp = (je > 0) ? (je - 1) : 0;
    float4 m[C]; bool act[C];
    #pragma unroll
    for (int t = 0; t < C; ++t) {
        int jj = j + t;
        act[t] = jj < je;
        m[t] = meta[act[t] ? jj : jclamp];
    }
    ushort2 hv[C]; float zv[C];
    #pragma unroll
    for (int t = 0; t < C; ++t) {
        int c = __builtin_bit_cast(int, m[t].x);
        hv[t] = ((const ushort2*)(hb + (size_t)c * 128))[lane];
        zv[t] = zj[(size_t)c * 64 + lane];
    }
    #pragma unroll
    for (int t = 0; t < C; ++t) {
        float es = act[t] ? (asr + m[t].y) : 0.f;
        acca.x += es * bf2f(hv[t].x);
        acca.y += es * bf2f(hv[t].y);
        zmax = fmaxf(zmax, act[t] ? zv[t] : -__builtin_inff());
        vfsum += act[t] ? m[t].z : 0.f;
    }
}

__global__ __launch_bounds__(256) void k_aggregate(
    const float4* __restrict__ meta, const int* __restrict__ rowptr,
    const float* __restrict__ h0, const unsigned short* __restrict__ hb,
    const float* __restrict__ zj,
    const float* __restrict__ a_self, const float* __restrict__ gpart,
    const float* __restrict__ Wg,
    const float* __restrict__ scale0, const float* __restrict__ offset0,
    const float* __restrict__ scale1, const float* __restrict__ offset1,
    float* __restrict__ out, int N) {
    int r = blockIdx.x * 4 + (threadIdx.x >> 6);
    int lane = threadIdx.x & 63;
    if (r >= N) return;
    int jb = rowptr[r], je = rowptr[r + 1];
    float2 acca = {0.f, 0.f};
    float zmax = -__builtin_inff();
    float vfsum = 0.f;
    float asr = a_self[r];
    for (int j = jb; j < je; j += 8)
        agg_chunk_m<8>(meta, j, je, lane, asr, hb, zj, acca, zmax, vfsum);
    if (jb == je) zmax = 0.f;  // empty segment: -inf -> 0
    float gs = zmax * Wg[128 + lane];
    #pragma unroll
    for (int off = 32; off; off >>= 1) gs += __shfl_xor(gs, off, 64);
    float gate = gpart[r] + gs + vfsum;  // all-f32 gate path (sign matters)
    float2 ag = {acca.x * gate, acca.y * gate};
    // BN on h0 row
    float2 x0 = ((const float2*)(h0 + (size_t)r * 128))[lane];
    float m0s = x0.x + x0.y;
    #pragma unroll
    for (int off = 32; off; off >>= 1) m0s += __shfl_xor(m0s, off, 64);
    float m0 = m0s * (1.f / 128.f);
    float d0x = x0.x - m0, d0y = x0.y - m0;
    float v0s = d0x * d0x + d0y * d0y;
    #pragma unroll
    for (int off = 32; off; off >>= 1) v0s += __shfl_xor(v0s, off, 64);
    float inv0 = rsqrtf(v0s * (1.f / 128.f) + 1e-9f);
    // BN on gated aggregation
    float m1s = ag.x + ag.y;
    #pragma unroll
    for (int off = 32; off; off >>= 1) m1s += __shfl_xor(m1s, off, 64);
    float m1 = m1s * (1.f / 128.f);
    float d1x = ag.x - m1, d1y = ag.y - m1;
    float v1s = d1x * d1x + d1y * d1y;
    #pragma unroll
    for (int off = 32; off; off >>= 1) v1s += __shfl_xor(v1s, off, 64);
    float inv1 = rsqrtf(v1s * (1.f / 128.f) + 1e-9f);
    float2 sc0 = ((const float2*)scale0)[lane], of0 = ((const float2*)offset0)[lane];
    float2 sc1 = ((const float2*)scale1)[lane], of1 = ((const float2*)offset1)[lane];
    float2 o;
    o.x = d0x * sc0.x * inv0 + of0.x + d1x * sc1.x * inv1 + of1.x;
    o.y = d0y * sc0.y * inv0 + of0.y + d1y * sc1.y * inv1 + of1.y;
    ((float2*)(out + (size_t)r * 128))[lane] = o;
}

extern "C" void kernel_launch(void* const* d_in, const int* in_sizes, int n_in,
                              void* d_out, int out_size, void* d_ws, size_t ws_size,
                              hipStream_t stream) {
    const int*   rows   = (const int*)d_in[0];
    const int*   cols   = (const int*)d_in[1];
    const float* vals   = (const float*)d_in[2];
    const float* feat   = (const float*)d_in[3];
    const float* W0     = (const float*)d_in[4];
    const float* b0     = (const float*)d_in[5];
    const float* W1     = (const float*)d_in[6];
    const float* b1     = (const float*)d_in[7];
    const float* att    = (const float*)d_in[8];
    const float* Wp     = (const float*)d_in[9];
    const float* Wg     = (const float*)d_in[10];
    const float* offset0 = (const float*)d_in[11];
    const float* scale0  = (const float*)d_in[12];
    const float* offset1 = (const float*)d_in[13];
    const float* scale1  = (const float*)d_in[14];
    float* out = (float*)d_out;

    const int E = in_sizes[0];
    const int N = in_sizes[3] / DIN;
    const int Npad = (N + 63) & ~63;

    char* ws = (char*)d_ws;
    float* h0          = (float*)ws;          ws += (size_t)N * 128 * sizeof(float);
    unsigned short* hb = (unsigned short*)ws; ws += (size_t)N * 128 * sizeof(unsigned short);
    float* zj          = (float*)ws;          ws += (size_t)N * 64 * sizeof(float);
    unsigned short* Bt = (unsigned short*)ws; ws += (size_t)256 * 128 * sizeof(unsigned short);
    float* a_self  = (float*)ws; ws += (size_t)N * sizeof(float);
    float* a_neigh = (float*)ws; ws += (size_t)N * sizeof(float);
    float* gpart   = (float*)ws; ws += (size_t)N * sizeof(float);
    float* fdotg   = (float*)ws; ws += (size_t)N * sizeof(float);
    ws = (char*)(((size_t)ws + 7) & ~(size_t)7);
    unsigned long long* bstate = (unsigned long long*)ws; ws += 64 * sizeof(unsigned long long);
    int* deg      = (int*)ws; ws += (size_t)(N + 1) * sizeof(int);
    int* rowptr   = (int*)ws; ws += (size_t)(N + 1) * sizeof(int);
    int* slot     = (int*)ws; ws += (size_t)E * sizeof(int);
    ws = (char*)(((size_t)ws + 15) & ~(size_t)15);
    float4* meta  = (float4*)ws; ws += (size_t)E * sizeof(float4);

    // zero bstate (flags) + deg in one memset (contiguous in ws)
    hipMemsetAsync(bstate, 0, 64 * sizeof(unsigned long long) + (size_t)(N + 1) * sizeof(int), stream);

    int nDeg = (E + 255) / 256;
    k_pre<<<nDeg + 128, 256, 0, stream>>>(rows, deg, slot, E, nDeg, W0, W1, Bt);

    int nbs = (N + 1023) >> 10;  // 49 for N=50000 (scan role blocks)
    dim3 gg(Npad / 64, 3);       // y=0: zj (x<ceil(N/128)), y=1: mfma, y=2: scan (x<nbs)
    k_fused<<<gg, 256, 0, stream>>>(feat, Wp, Bt, b0, b1, att, Wg,
                                    h0, hb, zj, gpart, fdotg, a_self, a_neigh,
                                    deg, rowptr, bstate, nbs, N);

    k_scatter_meta<<<nDeg, 256, 0, stream>>>(rows, cols, vals, rowptr, slot,
                                             a_neigh, fdotg, meta, E);

    int nb4 = (N + 3) / 4;
    k_aggregate<<<nb4, 256, 0, stream>>>(meta, rowptr, h0, hb, zj,
                                         a_self, gpart, Wg,
                                         scale0, offset0, scale1, offset1, out, N);
}